// Round 1
// baseline (35160.739 us; speedup 1.0000x reference)
//
#include <hip/hip_runtime.h>
#include <math.h>

#define VOCAB 20000
#define EDIM  100
#define HDIM  200
#define KTAG  17
#define BATCH 128
#define TLEN  512

// ws layout (float offsets)
static const size_t PROJ_OFF = 0;              // 2 * 20000 * 800 = 32,000,000 floats
static const size_t HBUF_OFF = 32000000;       // 2(parity) * 2(dir) * 128 * 200 = 102,400
static const size_t BAR_OFF  = 32102400;       // 64 u32 (16 group counters + 16 gens, padded)
static const size_t LSTM_OFF = 32102464;       // 512*128*400 = 26,214,400
static const size_t EM_OFF   = 58316864;       // 512*128*17 = 1,114,112
// total = 59,430,976 floats = 237,723,904 bytes

// ---------------- K1: per-vocab input projections ----------------
// proj[d][v][oj] with oj = e*4 + g  (g in torch gate order i,f,g,o), e in [0,200)
// proj value = sum_k W_ih[g*200+e][k] * emb[v][k]   (bias added later in K2)
__global__ __launch_bounds__(256) void k1_proj(const float* __restrict__ emb,
                                               const float* __restrict__ Wf,
                                               const float* __restrict__ Wb,
                                               float* __restrict__ ws)
{
    int blk = blockIdx.x;
    int d = blk / 313, vt = blk % 313;
    const float* Wih = d ? Wb : Wf;
    float* proj = ws + PROJ_OFF + (size_t)d * VOCAB * 800;
    __shared__ float elds[64][104];
    __shared__ float olds[64][4][26];
    int tid = threadIdx.x;
    for (int idx = tid; idx < 64 * EDIM; idx += 256) {
        int r = idx / EDIM, c = idx % EDIM;
        int v = vt * 64 + r;
        elds[r][c] = (v < VOCAB) ? emb[(size_t)v * EDIM + c] : 0.f;
    }
    __syncthreads();
    int lane = tid & 63, wq = tid >> 6;
    int v = vt * 64 + lane;
    float4 er[25];
#pragma unroll
    for (int i = 0; i < 25; i++) er[i] = *(const float4*)&elds[lane][4 * i];
#pragma unroll 1
    for (int round = 0; round < 8; round++) {
#pragma unroll 1
        for (int m = 0; m < 25; m++) {
            int oj = wq * 200 + round * 25 + m;      // wave-uniform
            int e = oj >> 2, g = oj & 3;
            int row = __builtin_amdgcn_readfirstlane(g * HDIM + e);
            const float* wrow = Wih + (size_t)row * EDIM;
            float acc = 0.f;
#pragma unroll
            for (int i = 0; i < 25; i++) {
                float4 w4 = *(const float4*)&wrow[4 * i];
                acc += w4.x * er[i].x + w4.y * er[i].y + w4.z * er[i].z + w4.w * er[i].w;
            }
            olds[lane][wq][m] = acc;
        }
        __syncthreads();
        for (int idx = tid; idx < 6400; idx += 256) {
            int vloc = idx / 100, rem = idx % 100;
            int q = rem / 25, c = rem % 25;
            int vv = vt * 64 + vloc;
            if (vv < VOCAB) proj[(size_t)vv * 800 + q * 200 + round * 25 + c] = olds[vloc][q][c];
        }
        __syncthreads();
    }
}

// ---------------- K2: bidirectional LSTM recurrence (persistent, cooperative) ----------------
// 256 wgs = dir(2) x elem-tile(16) x batch-tile(8). Each wg owns 13 (or 5) h-elems
// => 52 (20) gate rows x 16 batches. W_hh rows live in registers (k-quartered).
// One group barrier (16 wgs sharing (dir,batch-tile)) per timestep.
__global__ __launch_bounds__(256, 2) void k2_lstm(const int* __restrict__ sentence,
                                                  const float* __restrict__ Whh_f,
                                                  const float* __restrict__ bf,
                                                  const float* __restrict__ Whh_b,
                                                  const float* __restrict__ bb,
                                                  float* __restrict__ ws)
{
    int w = blockIdx.x;
    int d = w >> 7, rr = w & 127, et = rr >> 3, bt = rr & 7;
    int EN  = (et == 15) ? 5 : 13;
    int NR2 = 2 * EN;                 // number of row-pairs
    int E0  = et * 13;
    int B0  = bt * 16;
    const float* Whh  = d ? Whh_b : Whh_f;
    const float* bvec = d ? bb : bf;
    const float* proj = ws + PROJ_OFF + (size_t)d * VOCAB * 800;
    float* hbuf = ws + HBUF_OFF;
    unsigned int* bar = (unsigned int*)(ws + BAR_OFF);
    float* lstm_out = ws + LSTM_OFF;
    int grp = d * 8 + bt;

    __shared__ float hlds[16][208];
    __shared__ float glds[52][17];
    __shared__ int   toklds[16];

    int tid = threadIdx.x;
    int rp = tid >> 3, bp = (tid >> 2) & 1, kq = tid & 3;
    bool act = rp < NR2;
    int r0 = 2 * rp, r1 = 2 * rp + 1;
    float bias0 = 0.f, bias1 = 0.f;
    float4 w4[2][13];
#pragma unroll
    for (int i = 0; i < 13; i++) { w4[0][i] = make_float4(0.f,0.f,0.f,0.f); w4[1][i] = make_float4(0.f,0.f,0.f,0.f); }
    if (act) {
        int j0 = (r0 & 3) * HDIM + (E0 + (r0 >> 2));
        int j1 = (r1 & 3) * HDIM + (E0 + (r1 >> 2));
        bias0 = bvec[j0]; bias1 = bvec[j1];
#pragma unroll
        for (int i = 0; i < 13; i++) {
            int k = kq * 52 + 4 * i;
            if (k <= 196) {
                w4[0][i] = *(const float4*)&Whh[(size_t)j0 * HDIM + k];
                w4[1][i] = *(const float4*)&Whh[(size_t)j1 * HDIM + k];
            }
        }
    }
    if (tid < 128) { int b = tid >> 3, c = 200 + (tid & 7); hlds[b][c] = 0.f; }

    int ub = tid / 13, ue = tid % 13;            // update role: tid<208 => (batch, elem)
    bool uact = (tid < 208) && (ue < EN);
    float creg = 0.f;

#pragma unroll 1
    for (int t = 0; t < TLEN; t++) {
        int t_eff = d ? (TLEN - 1 - t) : t;
        if (tid < 16) toklds[tid] = sentence[(size_t)(B0 + tid) * TLEN + t_eff];
        __syncthreads();
        float xp0[8], xp1[8];
        if (act && kq == 0) {
#pragma unroll
            for (int bi = 0; bi < 8; bi++) {
                int tk = toklds[bp * 8 + bi];
                xp0[bi] = proj[(size_t)tk * 800 + E0 * 4 + r0];
                xp1[bi] = proj[(size_t)tk * 800 + E0 * 4 + r1];
            }
        }
        int pr = t & 1;
        const float* hsrc = hbuf + (size_t)(pr * 2 + d) * BATCH * HDIM;
#pragma unroll
        for (int s = 0; s < 4; s++) {
            int it = tid + 256 * s;
            if (it < 800) {
                int b = it / 50, c4 = it % 50;
                float4 v = *(const float4*)&hsrc[(size_t)(B0 + b) * HDIM + 4 * c4];
                *(float4*)&hlds[b][4 * c4] = v;
            }
        }
        __syncthreads();

        float acc[2][8];
#pragma unroll
        for (int x = 0; x < 2; x++)
#pragma unroll
            for (int bi = 0; bi < 8; bi++) acc[x][bi] = 0.f;
        int kbase = kq * 52;
#pragma unroll
        for (int i = 0; i < 13; i++) {
#pragma unroll
            for (int bi = 0; bi < 8; bi++) {
                float4 hv = *(const float4*)&hlds[bp * 8 + bi][kbase + 4 * i];
                acc[0][bi] += w4[0][i].x * hv.x + w4[0][i].y * hv.y + w4[0][i].z * hv.z + w4[0][i].w * hv.w;
                acc[1][bi] += w4[1][i].x * hv.x + w4[1][i].y * hv.y + w4[1][i].z * hv.z + w4[1][i].w * hv.w;
            }
        }
#pragma unroll
        for (int x = 0; x < 2; x++)
#pragma unroll
            for (int bi = 0; bi < 8; bi++) {
                acc[x][bi] += __shfl_xor(acc[x][bi], 1);
                acc[x][bi] += __shfl_xor(acc[x][bi], 2);
            }
        if (act && kq == 0) {
#pragma unroll
            for (int bi = 0; bi < 8; bi++) {
                glds[r0][bp * 8 + bi] = acc[0][bi] + xp0[bi] + bias0;
                glds[r1][bp * 8 + bi] = acc[1][bi] + xp1[bi] + bias1;
            }
        }
        __syncthreads();

        if (uact) {
            float gi = glds[ue * 4 + 0][ub];
            float gf = glds[ue * 4 + 1][ub];
            float gg = glds[ue * 4 + 2][ub];
            float go = glds[ue * 4 + 3][ub];
            float si = 1.f / (1.f + expf(-gi));
            float sf = 1.f / (1.f + expf(-gf));
            float so = 1.f / (1.f + expf(-go));
            creg = sf * creg + si * tanhf(gg);
            float hval = so * tanhf(creg);
            int pw = 1 - pr;
            hbuf[((size_t)(pw * 2 + d) * BATCH + B0 + ub) * HDIM + E0 + ue] = hval;
            lstm_out[((size_t)t_eff * BATCH + B0 + ub) * 400 + d * HDIM + E0 + ue] = hval;
        }
        __threadfence();
        __syncthreads();
        if (tid == 0) {
            unsigned arr = __hip_atomic_fetch_add(&bar[grp], 1u, __ATOMIC_ACQ_REL, __HIP_MEMORY_SCOPE_AGENT);
            if (arr == 15u) {
                __hip_atomic_store(&bar[grp], 0u, __ATOMIC_RELAXED, __HIP_MEMORY_SCOPE_AGENT);
                __hip_atomic_fetch_add(&bar[32 + grp], 1u, __ATOMIC_RELEASE, __HIP_MEMORY_SCOPE_AGENT);
            } else {
                while (__hip_atomic_load(&bar[32 + grp], __ATOMIC_ACQUIRE, __HIP_MEMORY_SCOPE_AGENT) < (unsigned)(t + 1)) {}
            }
        }
        __syncthreads();
    }
}

// ---------------- K3: emissions em = lstm_out @ W_fc^T + b_fc ----------------
__global__ __launch_bounds__(256) void k3_em(const float* __restrict__ Wfc,
                                             const float* __restrict__ bfc,
                                             float* __restrict__ ws)
{
    __shared__ float llds[15][404];
    __shared__ float wlds[17][404];
    const float* lstm = ws + LSTM_OFF;
    float* em = ws + EM_OFF;
    int n0 = blockIdx.x * 15;
    int tid = threadIdx.x;
    for (int idx = tid; idx < 15 * 400; idx += 256) {
        int r = idx / 400, c = idx % 400;
        int n = n0 + r;
        llds[r][c] = (n < BATCH * TLEN) ? lstm[(size_t)n * 400 + c] : 0.f;
    }
    for (int idx = tid; idx < 17 * 400; idx += 256) {
        int r = idx / 400, c = idx % 400;
        wlds[r][c] = Wfc[r * 400 + c];
    }
    __syncthreads();
    if (tid < 255) {
        int tk = tid / 17, k = tid % 17;
        int n = n0 + tk;
        if (n < BATCH * TLEN) {
            float acc = 0.f;
#pragma unroll
            for (int i = 0; i < 100; i++) {
                float4 a  = *(const float4*)&llds[tk][4 * i];
                float4 wv = *(const float4*)&wlds[k][4 * i];
                acc += a.x * wv.x + a.y * wv.y + a.z * wv.z + a.w * wv.w;
            }
            em[(size_t)n * KTAG + k] = acc + bfc[k];
        }
    }
}

// ---------------- K4: bin_scores = mean_t(lstm_out) @ W_bin^T + b_bin ----------------
__global__ __launch_bounds__(256) void k4_bin(const float* __restrict__ Wbin,
                                              const float* __restrict__ bbin,
                                              float* __restrict__ ws,
                                              float* __restrict__ out)
{
    int b = blockIdx.x, tid = threadIdx.x;
    const float* lstm = ws + LSTM_OFF;
    __shared__ float m_lds[400];
    float a0 = 0.f, a1 = 0.f;
#pragma unroll 4
    for (int t = 0; t < TLEN; t++) {
        const float* rowp = lstm + ((size_t)t * BATCH + b) * 400;
        a0 += rowp[tid];
        if (tid < 144) a1 += rowp[256 + tid];
    }
    m_lds[tid] = a0 * (1.f / 512.f);
    if (tid < 144) m_lds[256 + tid] = a1 * (1.f / 512.f);
    __syncthreads();
    int wv = tid >> 6, lane = tid & 63;
    if (wv < 2) {
        float p = 0.f;
        for (int j = lane; j < 400; j += 64) p += m_lds[j] * Wbin[wv * 400 + j];
#pragma unroll
        for (int off = 32; off > 0; off >>= 1) p += __shfl_down(p, off);
        if (lane == 0) out[(size_t)BATCH * TLEN + b * 2 + wv] = p + bbin[wv];
    }
}

// ---------------- K5: masked Viterbi decode + traceback ----------------
__global__ __launch_bounds__(64) void k5_vit(const int* __restrict__ masks,
                                             const float* __restrict__ trans,
                                             const float* __restrict__ startv,
                                             const float* __restrict__ endv,
                                             const float* __restrict__ ws,
                                             float* __restrict__ out)
{
    int b = blockIdx.x, lane = threadIdx.x;
    const float* em = ws + EM_OFF;
    __shared__ float emlds[TLEN * KTAG];
    __shared__ unsigned char bpl[TLEN * KTAG];
    __shared__ int mlds[TLEN];
    __shared__ unsigned char tagl[TLEN];
    __shared__ float slds[KTAG];
    __shared__ float fin[KTAG];

    for (int idx = lane; idx < TLEN * KTAG; idx += 64) {
        int tt = idx / KTAG, j = idx - tt * KTAG;
        emlds[idx] = em[((size_t)tt * BATCH + b) * KTAG + j];
    }
    for (int idx = lane; idx < TLEN; idx += 64) mlds[idx] = masks[(size_t)b * TLEN + idx];
    bool on = lane < KTAG;
    float tr[KTAG];
    if (on) {
#pragma unroll
        for (int i = 0; i < KTAG; i++) tr[i] = trans[i * KTAG + lane];
    }
    __syncthreads();
    float sown = 0.f;
    if (on) { sown = startv[lane] + emlds[lane]; slds[lane] = sown; }
    __syncthreads();
#pragma unroll 1
    for (int t = 1; t < TLEN; t++) {
        int m = mlds[t];
        float ns = sown; int idx = lane;
        if (on) {
            float best = -3.4e38f; int bi = 0;
#pragma unroll
            for (int i = 0; i < KTAG; i++) {
                float vv = slds[i] + tr[i];
                if (vv > best) { best = vv; bi = i; }   // strict > => first max (matches jnp.argmax)
            }
            if (m != 0) { ns = best + emlds[t * KTAG + lane]; idx = bi; }
        }
        __syncthreads();
        if (on) { sown = ns; slds[lane] = ns; bpl[t * KTAG + lane] = (unsigned char)idx; }
        __syncthreads();
    }
    if (on) fin[lane] = sown + endv[lane];
    __syncthreads();
    if (lane == 0) {
        float bb = -3.4e38f; int bi = 0;
#pragma unroll
        for (int i = 0; i < KTAG; i++) if (fin[i] > bb) { bb = fin[i]; bi = i; }
        int cur = bi;
        tagl[TLEN - 1] = (unsigned char)cur;
        for (int t = TLEN - 1; t >= 1; t--) {
            cur = bpl[t * KTAG + cur];
            tagl[t - 1] = (unsigned char)cur;
        }
    }
    __syncthreads();
    for (int s = lane; s < TLEN; s += 64) out[(size_t)b * TLEN + s] = (float)tagl[s];
}

extern "C" void kernel_launch(void* const* d_in, const int* in_sizes, int n_in,
                              void* d_out, int out_size, void* d_ws, size_t ws_size,
                              hipStream_t stream)
{
    (void)in_sizes; (void)n_in; (void)out_size; (void)ws_size;
    const int*   sentence = (const int*)d_in[0];
    const int*   masks    = (const int*)d_in[1];
    const float* emb      = (const float*)d_in[2];
    const float* Wih_f    = (const float*)d_in[3];
    const float* Whh_f    = (const float*)d_in[4];
    const float* b_f      = (const float*)d_in[5];
    const float* Wih_b    = (const float*)d_in[6];
    const float* Whh_b    = (const float*)d_in[7];
    const float* b_b      = (const float*)d_in[8];
    const float* W_fc     = (const float*)d_in[9];
    const float* b_fc     = (const float*)d_in[10];
    const float* W_bin    = (const float*)d_in[11];
    const float* b_bin    = (const float*)d_in[12];
    const float* trans    = (const float*)d_in[13];
    const float* startv   = (const float*)d_in[14];
    const float* endv     = (const float*)d_in[15];
    float* ws  = (float*)d_ws;
    float* out = (float*)d_out;

    // zero h-state (parity 0 read at t=0) + barrier words, every launch (deterministic)
    hipMemsetAsync(ws + HBUF_OFF, 0, (102400 + 64) * sizeof(float), stream);

    k1_proj<<<626, 256, 0, stream>>>(emb, Wih_f, Wih_b, ws);

    {
        const int* s_ = sentence; const float* wf_ = Whh_f; const float* bf_ = b_f;
        const float* wb_ = Whh_b; const float* bb_ = b_b; float* ws_ = ws;
        void* args[] = { (void*)&s_, (void*)&wf_, (void*)&bf_, (void*)&wb_, (void*)&bb_, (void*)&ws_ };
        hipLaunchCooperativeKernel((void*)k2_lstm, dim3(256), dim3(256), args, 0, stream);
    }

    k3_em<<<4370, 256, 0, stream>>>(W_fc, b_fc, ws);
    k4_bin<<<128, 256, 0, stream>>>(W_bin, b_bin, ws, out);
    k5_vit<<<128, 64, 0, stream>>>(masks, trans, startv, endv, ws, out);
}

// Round 2
// 32177.576 us; speedup vs baseline: 1.0927x; 1.0927x over previous
//
#include <hip/hip_runtime.h>
#include <math.h>

#define VOCAB 20000
#define EDIM  100
#define HDIM  200
#define KTAG  17
#define BATCH 128
#define TLEN  512

// ws layout (float offsets)
static const size_t PROJ_OFF = 0;              // 2 * 20000 * 800 = 32,000,000 floats
static const size_t HBUF_OFF = 32000000;       // 2(parity) * 2(dir) * 128 * 200 = 102,400
static const size_t LSTM_OFF = 32102464;       // 512*128*400 = 26,214,400
static const size_t EM_OFF   = 58316864;       // 512*128*17 = 1,114,112
// FLAGS overlap the EM region (dead until k3, which runs after k2):
// 16 groups * 16 wgs * 16 u32 (64B padding) = 4096 u32
static const size_t FLAGS_OFF = EM_OFF;
// total = 59,430,976 floats = 237,723,904 bytes (unchanged from R0)

// ---------------- K1: per-vocab input projections ----------------
__global__ __launch_bounds__(256) void k1_proj(const float* __restrict__ emb,
                                               const float* __restrict__ Wf,
                                               const float* __restrict__ Wb,
                                               float* __restrict__ ws)
{
    int blk = blockIdx.x;
    int d = blk / 313, vt = blk % 313;
    const float* Wih = d ? Wb : Wf;
    float* proj = ws + PROJ_OFF + (size_t)d * VOCAB * 800;
    __shared__ float elds[64][104];
    __shared__ float olds[64][4][26];
    int tid = threadIdx.x;
    for (int idx = tid; idx < 64 * EDIM; idx += 256) {
        int r = idx / EDIM, c = idx % EDIM;
        int v = vt * 64 + r;
        elds[r][c] = (v < VOCAB) ? emb[(size_t)v * EDIM + c] : 0.f;
    }
    __syncthreads();
    int lane = tid & 63, wq = tid >> 6;
    float4 er[25];
#pragma unroll
    for (int i = 0; i < 25; i++) er[i] = *(const float4*)&elds[lane][4 * i];
#pragma unroll 1
    for (int round = 0; round < 8; round++) {
#pragma unroll 1
        for (int m = 0; m < 25; m++) {
            int oj = wq * 200 + round * 25 + m;      // wave-uniform
            int e = oj >> 2, g = oj & 3;
            int row = __builtin_amdgcn_readfirstlane(g * HDIM + e);
            const float* wrow = Wih + (size_t)row * EDIM;
            float acc = 0.f;
#pragma unroll
            for (int i = 0; i < 25; i++) {
                float4 w4 = *(const float4*)&wrow[4 * i];
                acc += w4.x * er[i].x + w4.y * er[i].y + w4.z * er[i].z + w4.w * er[i].w;
            }
            olds[lane][wq][m] = acc;
        }
        __syncthreads();
        for (int idx = tid; idx < 6400; idx += 256) {
            int vloc = idx / 100, rem = idx % 100;
            int q = rem / 25, c = rem % 25;
            int vv = vt * 64 + vloc;
            if (vv < VOCAB) proj[(size_t)vv * 800 + q * 200 + round * 25 + c] = olds[vloc][q][c];
        }
        __syncthreads();
    }
}

// ---------------- K2: bidirectional LSTM recurrence (persistent, cooperative) ----------------
// 256 wgs = dir(2) x elem-tile(16) x batch-tile(8). Each wg owns 13 (or 5) h-elems.
// Inter-wg sync per step: distributed per-wg flags, 64B-padded, store-release +
// 16-lane parallel acquire-poll (NO shared-line RMWs — R0's barrier serialized
// 256 fabric RMWs/step on 2 cache lines => ~68us/step).
__global__ __launch_bounds__(256, 2) void k2_lstm(const int* __restrict__ sentence,
                                                  const float* __restrict__ Whh_f,
                                                  const float* __restrict__ bf,
                                                  const float* __restrict__ Whh_b,
                                                  const float* __restrict__ bb,
                                                  float* __restrict__ ws)
{
    int w = blockIdx.x;
    int d = w >> 7, rr = w & 127, et = rr >> 3, bt = rr & 7;
    int EN  = (et == 15) ? 5 : 13;
    int NR2 = 2 * EN;                 // number of row-pairs
    int E0  = et * 13;
    int B0  = bt * 16;
    const float* Whh  = d ? Whh_b : Whh_f;
    const float* bvec = d ? bb : bf;
    const float* proj = ws + PROJ_OFF + (size_t)d * VOCAB * 800;
    float* hbuf = ws + HBUF_OFF;
    float* lstm_out = ws + LSTM_OFF;
    int grp = d * 8 + bt;
    unsigned int* flagbase = (unsigned int*)(ws + FLAGS_OFF) + (size_t)grp * 256; // 16 wgs x 16 u32
    unsigned int* myflag = flagbase + (size_t)et * 16;

    __shared__ float hlds[16][208];
    __shared__ float glds[52][17];
    __shared__ int   toklds[2][16];

    int tid = threadIdx.x;
    int rp = tid >> 3, bp = (tid >> 2) & 1, kq = tid & 3;
    bool act = rp < NR2;
    int r0 = 2 * rp, r1 = 2 * rp + 1;
    float bias0 = 0.f, bias1 = 0.f;
    float4 w4[2][13];
#pragma unroll
    for (int i = 0; i < 13; i++) { w4[0][i] = make_float4(0.f,0.f,0.f,0.f); w4[1][i] = make_float4(0.f,0.f,0.f,0.f); }
    if (act) {
        int j0 = (r0 & 3) * HDIM + (E0 + (r0 >> 2));
        int j1 = (r1 & 3) * HDIM + (E0 + (r1 >> 2));
        bias0 = bvec[j0]; bias1 = bvec[j1];
#pragma unroll
        for (int i = 0; i < 13; i++) {
            int k = kq * 52 + 4 * i;
            if (k <= 196) {
                w4[0][i] = *(const float4*)&Whh[(size_t)j0 * HDIM + k];
                w4[1][i] = *(const float4*)&Whh[(size_t)j1 * HDIM + k];
            }
        }
    }
    if (tid < 128) { int b = tid >> 3, c = 200 + (tid & 7); hlds[b][c] = 0.f; }
    if (tid < 16) toklds[0][tid] = sentence[(size_t)(B0 + tid) * TLEN + (d ? (TLEN - 1) : 0)];

    int ub = tid / 13, ue = tid % 13;            // update role: tid<208 => (batch, elem)
    bool uact = (tid < 208) && (ue < EN);
    float creg = 0.f;
    __syncthreads();

#pragma unroll 1
    for (int t = 0; t < TLEN; t++) {
        int t_eff = d ? (TLEN - 1 - t) : t;
        // phase 1: gather x-projections + stage h into LDS
        float xp0[8], xp1[8];
        if (act && kq == 0) {
#pragma unroll
            for (int bi = 0; bi < 8; bi++) {
                int tk = toklds[t & 1][bp * 8 + bi];
                xp0[bi] = proj[(size_t)tk * 800 + E0 * 4 + r0];
                xp1[bi] = proj[(size_t)tk * 800 + E0 * 4 + r1];
            }
        }
        int pr = t & 1;
        const float* hsrc = hbuf + (size_t)(pr * 2 + d) * BATCH * HDIM;
#pragma unroll
        for (int s = 0; s < 4; s++) {
            int it = tid + 256 * s;
            if (it < 800) {
                int b = it / 50, c4 = it % 50;
                float4 v = *(const float4*)&hsrc[(size_t)(B0 + b) * HDIM + 4 * c4];
                *(float4*)&hlds[b][4 * c4] = v;
            }
        }
        __syncthreads();

        // phase 2: h @ Whh^T partial dots (k-quartered), reduce, write gates
        float acc[2][8];
#pragma unroll
        for (int x = 0; x < 2; x++)
#pragma unroll
            for (int bi = 0; bi < 8; bi++) acc[x][bi] = 0.f;
        int kbase = kq * 52;
#pragma unroll
        for (int i = 0; i < 13; i++) {
#pragma unroll
            for (int bi = 0; bi < 8; bi++) {
                float4 hv = *(const float4*)&hlds[bp * 8 + bi][kbase + 4 * i];
                acc[0][bi] += w4[0][i].x * hv.x + w4[0][i].y * hv.y + w4[0][i].z * hv.z + w4[0][i].w * hv.w;
                acc[1][bi] += w4[1][i].x * hv.x + w4[1][i].y * hv.y + w4[1][i].z * hv.z + w4[1][i].w * hv.w;
            }
        }
#pragma unroll
        for (int x = 0; x < 2; x++)
#pragma unroll
            for (int bi = 0; bi < 8; bi++) {
                acc[x][bi] += __shfl_xor(acc[x][bi], 1);
                acc[x][bi] += __shfl_xor(acc[x][bi], 2);
            }
        if (act && kq == 0) {
#pragma unroll
            for (int bi = 0; bi < 8; bi++) {
                glds[r0][bp * 8 + bi] = acc[0][bi] + xp0[bi] + bias0;
                glds[r1][bp * 8 + bi] = acc[1][bi] + xp1[bi] + bias1;
            }
        }
        __syncthreads();

        // phase 3: activations, c/h update, publish h; prefetch next tokens
        if (uact) {
            float gi = glds[ue * 4 + 0][ub];
            float gf = glds[ue * 4 + 1][ub];
            float gg = glds[ue * 4 + 2][ub];
            float go = glds[ue * 4 + 3][ub];
            float si = 1.f / (1.f + expf(-gi));
            float sf = 1.f / (1.f + expf(-gf));
            float so = 1.f / (1.f + expf(-go));
            creg = sf * creg + si * tanhf(gg);
            float hval = so * tanhf(creg);
            int pw = 1 - pr;
            hbuf[((size_t)(pw * 2 + d) * BATCH + B0 + ub) * HDIM + E0 + ue] = hval;
            lstm_out[((size_t)t_eff * BATCH + B0 + ub) * 400 + d * HDIM + E0 + ue] = hval;
        }
        if (tid < 16 && t + 1 < TLEN)
            toklds[(t + 1) & 1][tid] = sentence[(size_t)(B0 + tid) * TLEN + (d ? (TLEN - 2 - t) : (t + 1))];
        __threadfence();
        __syncthreads();

        // phase 4: distributed flag barrier (group of 16 wgs sharing (dir,batch-tile))
        if (tid == 0)
            __hip_atomic_store(myflag, (unsigned)(t + 1), __ATOMIC_RELEASE, __HIP_MEMORY_SCOPE_AGENT);
        if (tid < 16) {
            unsigned int* f = flagbase + (size_t)tid * 16;
            while (__hip_atomic_load(f, __ATOMIC_ACQUIRE, __HIP_MEMORY_SCOPE_AGENT) < (unsigned)(t + 1))
                __builtin_amdgcn_s_sleep(2);
        }
        __syncthreads();
    }
}

// ---------------- K3: emissions em = lstm_out @ W_fc^T + b_fc ----------------
__global__ __launch_bounds__(256) void k3_em(const float* __restrict__ Wfc,
                                             const float* __restrict__ bfc,
                                             float* __restrict__ ws)
{
    __shared__ float llds[15][404];
    __shared__ float wlds[17][404];
    const float* lstm = ws + LSTM_OFF;
    float* em = ws + EM_OFF;
    int n0 = blockIdx.x * 15;
    int tid = threadIdx.x;
    for (int idx = tid; idx < 15 * 400; idx += 256) {
        int r = idx / 400, c = idx % 400;
        int n = n0 + r;
        llds[r][c] = (n < BATCH * TLEN) ? lstm[(size_t)n * 400 + c] : 0.f;
    }
    for (int idx = tid; idx < 17 * 400; idx += 256) {
        int r = idx / 400, c = idx % 400;
        wlds[r][c] = Wfc[r * 400 + c];
    }
    __syncthreads();
    if (tid < 255) {
        int tk = tid / 17, k = tid % 17;
        int n = n0 + tk;
        if (n < BATCH * TLEN) {
            float acc = 0.f;
#pragma unroll
            for (int i = 0; i < 100; i++) {
                float4 a  = *(const float4*)&llds[tk][4 * i];
                float4 wv = *(const float4*)&wlds[k][4 * i];
                acc += a.x * wv.x + a.y * wv.y + a.z * wv.z + a.w * wv.w;
            }
            em[(size_t)n * KTAG + k] = acc + bfc[k];
        }
    }
}

// ---------------- K4: bin_scores = mean_t(lstm_out) @ W_bin^T + b_bin ----------------
__global__ __launch_bounds__(256) void k4_bin(const float* __restrict__ Wbin,
                                              const float* __restrict__ bbin,
                                              float* __restrict__ ws,
                                              float* __restrict__ out)
{
    int b = blockIdx.x, tid = threadIdx.x;
    const float* lstm = ws + LSTM_OFF;
    __shared__ float m_lds[400];
    float a0 = 0.f, a1 = 0.f;
#pragma unroll 4
    for (int t = 0; t < TLEN; t++) {
        const float* rowp = lstm + ((size_t)t * BATCH + b) * 400;
        a0 += rowp[tid];
        if (tid < 144) a1 += rowp[256 + tid];
    }
    m_lds[tid] = a0 * (1.f / 512.f);
    if (tid < 144) m_lds[256 + tid] = a1 * (1.f / 512.f);
    __syncthreads();
    int wv = tid >> 6, lane = tid & 63;
    if (wv < 2) {
        float p = 0.f;
        for (int j = lane; j < 400; j += 64) p += m_lds[j] * Wbin[wv * 400 + j];
#pragma unroll
        for (int off = 32; off > 0; off >>= 1) p += __shfl_down(p, off);
        if (lane == 0) out[(size_t)BATCH * TLEN + b * 2 + wv] = p + bbin[wv];
    }
}

// ---------------- K5: masked Viterbi decode + traceback ----------------
__global__ __launch_bounds__(64) void k5_vit(const int* __restrict__ masks,
                                             const float* __restrict__ trans,
                                             const float* __restrict__ startv,
                                             const float* __restrict__ endv,
                                             const float* __restrict__ ws,
                                             float* __restrict__ out)
{
    int b = blockIdx.x, lane = threadIdx.x;
    const float* em = ws + EM_OFF;
    __shared__ float emlds[TLEN * KTAG];
    __shared__ unsigned char bpl[TLEN * KTAG];
    __shared__ int mlds[TLEN];
    __shared__ unsigned char tagl[TLEN];
    __shared__ float slds[KTAG];
    __shared__ float fin[KTAG];

    for (int idx = lane; idx < TLEN * KTAG; idx += 64) {
        int tt = idx / KTAG, j = idx - tt * KTAG;
        emlds[idx] = em[((size_t)tt * BATCH + b) * KTAG + j];
    }
    for (int idx = lane; idx < TLEN; idx += 64) mlds[idx] = masks[(size_t)b * TLEN + idx];
    bool on = lane < KTAG;
    float tr[KTAG];
    if (on) {
#pragma unroll
        for (int i = 0; i < KTAG; i++) tr[i] = trans[i * KTAG + lane];
    }
    __syncthreads();
    float sown = 0.f;
    if (on) { sown = startv[lane] + emlds[lane]; slds[lane] = sown; }
    __syncthreads();
#pragma unroll 1
    for (int t = 1; t < TLEN; t++) {
        int m = mlds[t];
        float ns = sown; int idx = lane;
        if (on) {
            float best = -3.4e38f; int bi = 0;
#pragma unroll
            for (int i = 0; i < KTAG; i++) {
                float vv = slds[i] + tr[i];
                if (vv > best) { best = vv; bi = i; }   // strict > => first max (matches jnp.argmax)
            }
            if (m != 0) { ns = best + emlds[t * KTAG + lane]; idx = bi; }
        }
        __syncthreads();
        if (on) { sown = ns; slds[lane] = ns; bpl[t * KTAG + lane] = (unsigned char)idx; }
        __syncthreads();
    }
    if (on) fin[lane] = sown + endv[lane];
    __syncthreads();
    if (lane == 0) {
        float bb = -3.4e38f; int bi = 0;
#pragma unroll
        for (int i = 0; i < KTAG; i++) if (fin[i] > bb) { bb = fin[i]; bi = i; }
        int cur = bi;
        tagl[TLEN - 1] = (unsigned char)cur;
        for (int t = TLEN - 1; t >= 1; t--) {
            cur = bpl[t * KTAG + cur];
            tagl[t - 1] = (unsigned char)cur;
        }
    }
    __syncthreads();
    for (int s = lane; s < TLEN; s += 64) out[(size_t)b * TLEN + s] = (float)tagl[s];
}

extern "C" void kernel_launch(void* const* d_in, const int* in_sizes, int n_in,
                              void* d_out, int out_size, void* d_ws, size_t ws_size,
                              hipStream_t stream)
{
    (void)in_sizes; (void)n_in; (void)out_size; (void)ws_size;
    const int*   sentence = (const int*)d_in[0];
    const int*   masks    = (const int*)d_in[1];
    const float* emb      = (const float*)d_in[2];
    const float* Wih_f    = (const float*)d_in[3];
    const float* Whh_f    = (const float*)d_in[4];
    const float* b_f      = (const float*)d_in[5];
    const float* Wih_b    = (const float*)d_in[6];
    const float* Whh_b    = (const float*)d_in[7];
    const float* b_b      = (const float*)d_in[8];
    const float* W_fc     = (const float*)d_in[9];
    const float* b_fc     = (const float*)d_in[10];
    const float* W_bin    = (const float*)d_in[11];
    const float* b_bin    = (const float*)d_in[12];
    const float* trans    = (const float*)d_in[13];
    const float* startv   = (const float*)d_in[14];
    const float* endv     = (const float*)d_in[15];
    float* ws  = (float*)d_ws;
    float* out = (float*)d_out;

    // zero h-state (parity 0 read at t=0) and sync flags, every launch (deterministic)
    hipMemsetAsync(ws + HBUF_OFF, 0, 102400 * sizeof(float), stream);
    hipMemsetAsync(ws + FLAGS_OFF, 0, 4096 * sizeof(float), stream);

    k1_proj<<<626, 256, 0, stream>>>(emb, Wih_f, Wih_b, ws);

    {
        const int* s_ = sentence; const float* wf_ = Whh_f; const float* bf_ = b_f;
        const float* wb_ = Whh_b; const float* bb_ = b_b; float* ws_ = ws;
        void* args[] = { (void*)&s_, (void*)&wf_, (void*)&bf_, (void*)&wb_, (void*)&bb_, (void*)&ws_ };
        hipLaunchCooperativeKernel((void*)k2_lstm, dim3(256), dim3(256), args, 0, stream);
    }

    k3_em<<<4370, 256, 0, stream>>>(W_fc, b_fc, ws);
    k4_bin<<<128, 256, 0, stream>>>(W_bin, b_bin, ws, out);
    k5_vit<<<128, 64, 0, stream>>>(masks, trans, startv, endv, ws, out);
}

// Round 3
// 17640.079 us; speedup vs baseline: 1.9932x; 1.8241x over previous
//
#include <hip/hip_runtime.h>
#include <math.h>

#define VOCAB 20000
#define EDIM  100
#define HDIM  200
#define KTAG  17
#define BATCH 128
#define TLEN  512

// ws layout (float offsets)
static const size_t PROJ_OFF = 0;              // 2 * 20000 * 800 = 32,000,000 floats
static const size_t HBUF_OFF = 32000000;       // 2(parity) * 2(dir) * 128 * 200 = 102,400
static const size_t LSTM_OFF = 32102464;       // 512*128*400 = 26,214,400
static const size_t EM_OFF   = 58316864;       // 512*128*17 = 1,114,112
// FLAGS overlap the EM region (dead until k3, which runs after k2):
static const size_t FLAGS_OFF = EM_OFF;        // 16 groups * 16 wgs * 16 u32 (64B padded)
// total = 59,430,976 floats = 237,723,904 bytes

// ---------------- K1: per-vocab input projections ----------------
__global__ __launch_bounds__(256) void k1_proj(const float* __restrict__ emb,
                                               const float* __restrict__ Wf,
                                               const float* __restrict__ Wb,
                                               float* __restrict__ ws)
{
    int blk = blockIdx.x;
    int d = blk / 313, vt = blk % 313;
    const float* Wih = d ? Wb : Wf;
    float* proj = ws + PROJ_OFF + (size_t)d * VOCAB * 800;
    __shared__ float elds[64][104];
    __shared__ float olds[64][4][26];
    int tid = threadIdx.x;
    for (int idx = tid; idx < 64 * EDIM; idx += 256) {
        int r = idx / EDIM, c = idx % EDIM;
        int v = vt * 64 + r;
        elds[r][c] = (v < VOCAB) ? emb[(size_t)v * EDIM + c] : 0.f;
    }
    __syncthreads();
    int lane = tid & 63, wq = tid >> 6;
    float4 er[25];
#pragma unroll
    for (int i = 0; i < 25; i++) er[i] = *(const float4*)&elds[lane][4 * i];
#pragma unroll 1
    for (int round = 0; round < 8; round++) {
#pragma unroll 1
        for (int m = 0; m < 25; m++) {
            int oj = wq * 200 + round * 25 + m;      // wave-uniform
            int e = oj >> 2, g = oj & 3;
            int row = __builtin_amdgcn_readfirstlane(g * HDIM + e);
            const float* wrow = Wih + (size_t)row * EDIM;
            float acc = 0.f;
#pragma unroll
            for (int i = 0; i < 25; i++) {
                float4 w4 = *(const float4*)&wrow[4 * i];
                acc += w4.x * er[i].x + w4.y * er[i].y + w4.z * er[i].z + w4.w * er[i].w;
            }
            olds[lane][wq][m] = acc;
        }
        __syncthreads();
        for (int idx = tid; idx < 6400; idx += 256) {
            int vloc = idx / 100, rem = idx % 100;
            int q = rem / 25, c = rem % 25;
            int vv = vt * 64 + vloc;
            if (vv < VOCAB) proj[(size_t)vv * 800 + q * 200 + round * 25 + c] = olds[vloc][q][c];
        }
        __syncthreads();
    }
}

// ---------------- K2: bidirectional LSTM recurrence (persistent, cooperative) ----------------
// Sync redesign (R2): RELAXED flag store + RELAXED polls (no per-op cache
// maintenance on gfx950) + exactly ONE release fence and ONE acquire fence per
// wg per step. R1's ACQUIRE-per-poll emitted a full L2 invalidate per poll
// (~1000/step/wg) => 25 GB fabric churn, 2.8% VALUBusy.
__global__ __launch_bounds__(256, 2) void k2_lstm(const int* __restrict__ sentence,
                                                  const float* __restrict__ Whh_f,
                                                  const float* __restrict__ bf,
                                                  const float* __restrict__ Whh_b,
                                                  const float* __restrict__ bb,
                                                  float* __restrict__ ws)
{
    int w = blockIdx.x;
    int d = w >> 7, rr = w & 127, et = rr >> 3, bt = rr & 7;
    int EN  = (et == 15) ? 5 : 13;
    int NR2 = 2 * EN;                 // number of row-pairs
    int E0  = et * 13;
    int B0  = bt * 16;
    const float* Whh  = d ? Whh_b : Whh_f;
    const float* bvec = d ? bb : bf;
    const float* proj = ws + PROJ_OFF + (size_t)d * VOCAB * 800;
    float* hbuf = ws + HBUF_OFF;
    float* lstm_out = ws + LSTM_OFF;
    int grp = d * 8 + bt;
    unsigned int* flagbase = (unsigned int*)(ws + FLAGS_OFF) + (size_t)grp * 256; // 16 wgs x 16 u32
    unsigned int* myflag = flagbase + (size_t)et * 16;

    __shared__ float hlds[16][208];
    __shared__ float glds[52][17];
    __shared__ int   toklds[2][16];

    int tid = threadIdx.x;
    int rp = tid >> 3, bp = (tid >> 2) & 1, kq = tid & 3;
    bool act = rp < NR2;
    int r0 = 2 * rp, r1 = 2 * rp + 1;
    float bias0 = 0.f, bias1 = 0.f;
    float4 w4[2][13];
#pragma unroll
    for (int i = 0; i < 13; i++) { w4[0][i] = make_float4(0.f,0.f,0.f,0.f); w4[1][i] = make_float4(0.f,0.f,0.f,0.f); }
    if (act) {
        int j0 = (r0 & 3) * HDIM + (E0 + (r0 >> 2));
        int j1 = (r1 & 3) * HDIM + (E0 + (r1 >> 2));
        bias0 = bvec[j0]; bias1 = bvec[j1];
#pragma unroll
        for (int i = 0; i < 13; i++) {
            int k = kq * 52 + 4 * i;
            if (k <= 196) {
                w4[0][i] = *(const float4*)&Whh[(size_t)j0 * HDIM + k];
                w4[1][i] = *(const float4*)&Whh[(size_t)j1 * HDIM + k];
            }
        }
    }
    if (tid < 128) { int b = tid >> 3, c = 200 + (tid & 7); hlds[b][c] = 0.f; }
    if (tid < 16) toklds[0][tid] = sentence[(size_t)(B0 + tid) * TLEN + (d ? (TLEN - 1) : 0)];

    int ub = tid / 13, ue = tid % 13;            // update role: tid<208 => (batch, elem)
    bool uact = (tid < 208) && (ue < EN);
    float creg = 0.f;
    __syncthreads();

#pragma unroll 1
    for (int t = 0; t < TLEN; t++) {
        int t_eff = d ? (TLEN - 1 - t) : t;
        // phase 1: gather x-projections + stage h into LDS
        float xp0[8], xp1[8];
        if (act && kq == 0) {
#pragma unroll
            for (int bi = 0; bi < 8; bi++) {
                int tk = toklds[t & 1][bp * 8 + bi];
                xp0[bi] = proj[(size_t)tk * 800 + E0 * 4 + r0];
                xp1[bi] = proj[(size_t)tk * 800 + E0 * 4 + r1];
            }
        }
        int pr = t & 1;
        const float* hsrc = hbuf + (size_t)(pr * 2 + d) * BATCH * HDIM;
#pragma unroll
        for (int s = 0; s < 4; s++) {
            int it = tid + 256 * s;
            if (it < 800) {
                int b = it / 50, c4 = it % 50;
                float4 v = *(const float4*)&hsrc[(size_t)(B0 + b) * HDIM + 4 * c4];
                *(float4*)&hlds[b][4 * c4] = v;
            }
        }
        __syncthreads();

        // phase 2: h @ Whh^T partial dots (k-quartered), reduce, write gates
        float acc[2][8];
#pragma unroll
        for (int x = 0; x < 2; x++)
#pragma unroll
            for (int bi = 0; bi < 8; bi++) acc[x][bi] = 0.f;
        int kbase = kq * 52;
#pragma unroll
        for (int i = 0; i < 13; i++) {
#pragma unroll
            for (int bi = 0; bi < 8; bi++) {
                float4 hv = *(const float4*)&hlds[bp * 8 + bi][kbase + 4 * i];
                acc[0][bi] += w4[0][i].x * hv.x + w4[0][i].y * hv.y + w4[0][i].z * hv.z + w4[0][i].w * hv.w;
                acc[1][bi] += w4[1][i].x * hv.x + w4[1][i].y * hv.y + w4[1][i].z * hv.z + w4[1][i].w * hv.w;
            }
        }
#pragma unroll
        for (int x = 0; x < 2; x++)
#pragma unroll
            for (int bi = 0; bi < 8; bi++) {
                acc[x][bi] += __shfl_xor(acc[x][bi], 1);
                acc[x][bi] += __shfl_xor(acc[x][bi], 2);
            }
        if (act && kq == 0) {
#pragma unroll
            for (int bi = 0; bi < 8; bi++) {
                glds[r0][bp * 8 + bi] = acc[0][bi] + xp0[bi] + bias0;
                glds[r1][bp * 8 + bi] = acc[1][bi] + xp1[bi] + bias1;
            }
        }
        __syncthreads();

        // phase 3: activations, c/h update, publish h; prefetch next tokens
        if (uact) {
            float gi = glds[ue * 4 + 0][ub];
            float gf = glds[ue * 4 + 1][ub];
            float gg = glds[ue * 4 + 2][ub];
            float go = glds[ue * 4 + 3][ub];
            float si = 1.f / (1.f + expf(-gi));
            float sf = 1.f / (1.f + expf(-gf));
            float so = 1.f / (1.f + expf(-go));
            creg = sf * creg + si * tanhf(gg);
            float hval = so * tanhf(creg);
            int pw = 1 - pr;
            hbuf[((size_t)(pw * 2 + d) * BATCH + B0 + ub) * HDIM + E0 + ue] = hval;
            lstm_out[((size_t)t_eff * BATCH + B0 + ub) * 400 + d * HDIM + E0 + ue] = hval;
        }
        if (tid < 16 && t + 1 < TLEN)
            toklds[(t + 1) & 1][tid] = sentence[(size_t)(B0 + tid) * TLEN + (d ? (TLEN - 2 - t) : (t + 1))];
        __syncthreads();   // all wg stores issued+drained (barrier drains vmcnt)

        // phase 4: one release fence + relaxed flag + relaxed polls + one acquire fence
        if (tid == 0) {
            __builtin_amdgcn_fence(__ATOMIC_RELEASE, "agent");   // single wbl2
            __hip_atomic_store(myflag, (unsigned)(t + 1), __ATOMIC_RELAXED, __HIP_MEMORY_SCOPE_AGENT);
        }
        if (tid < 16) {
            unsigned int* f = flagbase + (size_t)tid * 16;
            while (__hip_atomic_load(f, __ATOMIC_RELAXED, __HIP_MEMORY_SCOPE_AGENT) < (unsigned)(t + 1))
                __builtin_amdgcn_s_sleep(2);
            __builtin_amdgcn_fence(__ATOMIC_ACQUIRE, "agent");   // single inv (covers CU's L1 too)
        }
        __syncthreads();
    }
}

// ---------------- K3: emissions em = lstm_out @ W_fc^T + b_fc ----------------
__global__ __launch_bounds__(256) void k3_em(const float* __restrict__ Wfc,
                                             const float* __restrict__ bfc,
                                             float* __restrict__ ws)
{
    __shared__ float llds[15][404];
    __shared__ float wlds[17][404];
    const float* lstm = ws + LSTM_OFF;
    float* em = ws + EM_OFF;
    int n0 = blockIdx.x * 15;
    int tid = threadIdx.x;
    for (int idx = tid; idx < 15 * 400; idx += 256) {
        int r = idx / 400, c = idx % 400;
        int n = n0 + r;
        llds[r][c] = (n < BATCH * TLEN) ? lstm[(size_t)n * 400 + c] : 0.f;
    }
    for (int idx = tid; idx < 17 * 400; idx += 256) {
        int r = idx / 400, c = idx % 400;
        wlds[r][c] = Wfc[r * 400 + c];
    }
    __syncthreads();
    if (tid < 255) {
        int tk = tid / 17, k = tid % 17;
        int n = n0 + tk;
        if (n < BATCH * TLEN) {
            float acc = 0.f;
#pragma unroll
            for (int i = 0; i < 100; i++) {
                float4 a  = *(const float4*)&llds[tk][4 * i];
                float4 wv = *(const float4*)&wlds[k][4 * i];
                acc += a.x * wv.x + a.y * wv.y + a.z * wv.z + a.w * wv.w;
            }
            em[(size_t)n * KTAG + k] = acc + bfc[k];
        }
    }
}

// ---------------- K4: bin_scores = mean_t(lstm_out) @ W_bin^T + b_bin ----------------
__global__ __launch_bounds__(256) void k4_bin(const float* __restrict__ Wbin,
                                              const float* __restrict__ bbin,
                                              float* __restrict__ ws,
                                              float* __restrict__ out)
{
    int b = blockIdx.x, tid = threadIdx.x;
    const float* lstm = ws + LSTM_OFF;
    __shared__ float m_lds[400];
    float a0 = 0.f, a1 = 0.f;
#pragma unroll 4
    for (int t = 0; t < TLEN; t++) {
        const float* rowp = lstm + ((size_t)t * BATCH + b) * 400;
        a0 += rowp[tid];
        if (tid < 144) a1 += rowp[256 + tid];
    }
    m_lds[tid] = a0 * (1.f / 512.f);
    if (tid < 144) m_lds[256 + tid] = a1 * (1.f / 512.f);
    __syncthreads();
    int wv = tid >> 6, lane = tid & 63;
    if (wv < 2) {
        float p = 0.f;
        for (int j = lane; j < 400; j += 64) p += m_lds[j] * Wbin[wv * 400 + j];
#pragma unroll
        for (int off = 32; off > 0; off >>= 1) p += __shfl_down(p, off);
        if (lane == 0) out[(size_t)BATCH * TLEN + b * 2 + wv] = p + bbin[wv];
    }
}

// ---------------- K5: masked Viterbi decode + traceback ----------------
__global__ __launch_bounds__(64) void k5_vit(const int* __restrict__ masks,
                                             const float* __restrict__ trans,
                                             const float* __restrict__ startv,
                                             const float* __restrict__ endv,
                                             const float* __restrict__ ws,
                                             float* __restrict__ out)
{
    int b = blockIdx.x, lane = threadIdx.x;
    const float* em = ws + EM_OFF;
    __shared__ float emlds[TLEN * KTAG];
    __shared__ unsigned char bpl[TLEN * KTAG];
    __shared__ int mlds[TLEN];
    __shared__ unsigned char tagl[TLEN];
    __shared__ float slds[KTAG];
    __shared__ float fin[KTAG];

    for (int idx = lane; idx < TLEN * KTAG; idx += 64) {
        int tt = idx / KTAG, j = idx - tt * KTAG;
        emlds[idx] = em[((size_t)tt * BATCH + b) * KTAG + j];
    }
    for (int idx = lane; idx < TLEN; idx += 64) mlds[idx] = masks[(size_t)b * TLEN + idx];
    bool on = lane < KTAG;
    float tr[KTAG];
    if (on) {
#pragma unroll
        for (int i = 0; i < KTAG; i++) tr[i] = trans[i * KTAG + lane];
    }
    __syncthreads();
    float sown = 0.f;
    if (on) { sown = startv[lane] + emlds[lane]; slds[lane] = sown; }
    __syncthreads();
#pragma unroll 1
    for (int t = 1; t < TLEN; t++) {
        int m = mlds[t];
        float ns = sown; int idx = lane;
        if (on) {
            float best = -3.4e38f; int bi = 0;
#pragma unroll
            for (int i = 0; i < KTAG; i++) {
                float vv = slds[i] + tr[i];
                if (vv > best) { best = vv; bi = i; }   // strict > => first max (matches jnp.argmax)
            }
            if (m != 0) { ns = best + emlds[t * KTAG + lane]; idx = bi; }
        }
        __syncthreads();
        if (on) { sown = ns; slds[lane] = ns; bpl[t * KTAG + lane] = (unsigned char)idx; }
        __syncthreads();
    }
    if (on) fin[lane] = sown + endv[lane];
    __syncthreads();
    if (lane == 0) {
        float bb = -3.4e38f; int bi = 0;
#pragma unroll
        for (int i = 0; i < KTAG; i++) if (fin[i] > bb) { bb = fin[i]; bi = i; }
        int cur = bi;
        tagl[TLEN - 1] = (unsigned char)cur;
        for (int t = TLEN - 1; t >= 1; t--) {
            cur = bpl[t * KTAG + cur];
            tagl[t - 1] = (unsigned char)cur;
        }
    }
    __syncthreads();
    for (int s = lane; s < TLEN; s += 64) out[(size_t)b * TLEN + s] = (float)tagl[s];
}

extern "C" void kernel_launch(void* const* d_in, const int* in_sizes, int n_in,
                              void* d_out, int out_size, void* d_ws, size_t ws_size,
                              hipStream_t stream)
{
    (void)in_sizes; (void)n_in; (void)out_size; (void)ws_size;
    const int*   sentence = (const int*)d_in[0];
    const int*   masks    = (const int*)d_in[1];
    const float* emb      = (const float*)d_in[2];
    const float* Wih_f    = (const float*)d_in[3];
    const float* Whh_f    = (const float*)d_in[4];
    const float* b_f      = (const float*)d_in[5];
    const float* Wih_b    = (const float*)d_in[6];
    const float* Whh_b    = (const float*)d_in[7];
    const float* b_b      = (const float*)d_in[8];
    const float* W_fc     = (const float*)d_in[9];
    const float* b_fc     = (const float*)d_in[10];
    const float* W_bin    = (const float*)d_in[11];
    const float* b_bin    = (const float*)d_in[12];
    const float* trans    = (const float*)d_in[13];
    const float* startv   = (const float*)d_in[14];
    const float* endv     = (const float*)d_in[15];
    float* ws  = (float*)d_ws;
    float* out = (float*)d_out;

    // zero h-state (parity 0 read at t=0) and sync flags, every launch (deterministic)
    hipMemsetAsync(ws + HBUF_OFF, 0, 102400 * sizeof(float), stream);
    hipMemsetAsync(ws + FLAGS_OFF, 0, 4096 * sizeof(float), stream);

    k1_proj<<<626, 256, 0, stream>>>(emb, Wih_f, Wih_b, ws);

    {
        const int* s_ = sentence; const float* wf_ = Whh_f; const float* bf_ = b_f;
        const float* wb_ = Whh_b; const float* bb_ = b_b; float* ws_ = ws;
        void* args[] = { (void*)&s_, (void*)&wf_, (void*)&bf_, (void*)&wb_, (void*)&bb_, (void*)&ws_ };
        hipLaunchCooperativeKernel((void*)k2_lstm, dim3(256), dim3(256), args, 0, stream);
    }

    k3_em<<<4370, 256, 0, stream>>>(W_fc, b_fc, ws);
    k4_bin<<<128, 256, 0, stream>>>(W_bin, b_bin, ws, out);
    k5_vit<<<128, 64, 0, stream>>>(masks, trans, startv, endv, ws, out);
}

// Round 5
// 13013.333 us; speedup vs baseline: 2.7019x; 1.3555x over previous
//
#include <hip/hip_runtime.h>
#include <math.h>

#define VOCAB 20000
#define EDIM  100
#define HDIM  200
#define KTAG  17
#define BATCH 128
#define TLEN  512

// ws layout (float offsets)
static const size_t PROJ_OFF = 0;              // 2 * 20000 * 800 = 32,000,000 floats
static const size_t HBUF_OFF = 32000000;       // 2(parity) * 2(dir) * 128 * 200 = 102,400
static const size_t LSTM_OFF = 32102464;       // 512*128*400 = 26,214,400
static const size_t EM_OFF   = 58316864;       // 512*128*17 = 1,114,112
// FLAGS overlap the EM region (dead until k3):
static const size_t FLAGS_OFF = EM_OFF;        // 16 groups * 16 wgs * 16 u32 (64B padded) = 4096 u32
// total = 59,430,976 floats = 237,723,904 bytes

// ---------------- K1: per-vocab input projections ----------------
__global__ __launch_bounds__(256) void k1_proj(const float* __restrict__ emb,
                                               const float* __restrict__ Wf,
                                               const float* __restrict__ Wb,
                                               float* __restrict__ ws)
{
    int blk = blockIdx.x;
    int d = blk / 313, vt = blk % 313;
    const float* Wih = d ? Wb : Wf;
    float* proj = ws + PROJ_OFF + (size_t)d * VOCAB * 800;
    __shared__ float elds[64][104];
    __shared__ float olds[64][4][26];
    int tid = threadIdx.x;
    for (int idx = tid; idx < 64 * EDIM; idx += 256) {
        int r = idx / EDIM, c = idx % EDIM;
        int v = vt * 64 + r;
        elds[r][c] = (v < VOCAB) ? emb[(size_t)v * EDIM + c] : 0.f;
    }
    __syncthreads();
    int lane = tid & 63, wq = tid >> 6;
    float4 er[25];
#pragma unroll
    for (int i = 0; i < 25; i++) er[i] = *(const float4*)&elds[lane][4 * i];
#pragma unroll 1
    for (int round = 0; round < 8; round++) {
#pragma unroll 1
        for (int m = 0; m < 25; m++) {
            int oj = wq * 200 + round * 25 + m;      // wave-uniform
            int e = oj >> 2, g = oj & 3;
            int row = __builtin_amdgcn_readfirstlane(g * HDIM + e);
            const float* wrow = Wih + (size_t)row * EDIM;
            float acc = 0.f;
#pragma unroll
            for (int i = 0; i < 25; i++) {
                float4 w4 = *(const float4*)&wrow[4 * i];
                acc += w4.x * er[i].x + w4.y * er[i].y + w4.z * er[i].z + w4.w * er[i].w;
            }
            olds[lane][wq][m] = acc;
        }
        __syncthreads();
        for (int idx = tid; idx < 6400; idx += 256) {
            int vloc = idx / 100, rem = idx % 100;
            int q = rem / 25, c = rem % 25;
            int vv = vt * 64 + vloc;
            if (vv < VOCAB) proj[(size_t)vv * 800 + q * 200 + round * 25 + c] = olds[vloc][q][c];
        }
        __syncthreads();
    }
}

// ---------------- K2: bidirectional LSTM recurrence (persistent, cooperative) ----------------
// R4 sync redesign: ALL cross-wg state (h double-buffer + flags) uses relaxed
// agent-scope atomics (write-through to the device coherence point; loads
// bypass stale local caches). ZERO fences, ZERO cache-maintenance ops in the
// steady state. Ordering: relaxed h-stores -> __syncthreads (vmcnt drain =
// stores acked at coherence point) -> relaxed flag store; readers poll flags
// (R3's proven loop) then relaxed-load h. Placement-independent.
__global__ __launch_bounds__(256, 2) void k2_lstm(const int* __restrict__ sentence,
                                                  const float* __restrict__ Whh_f,
                                                  const float* __restrict__ bf,
                                                  const float* __restrict__ Whh_b,
                                                  const float* __restrict__ bb,
                                                  float* __restrict__ ws)
{
    int w = blockIdx.x;
    int d = w >> 7, rr = w & 127, et = rr >> 3, bt = rr & 7;
    int EN  = (et == 15) ? 5 : 13;
    int NR2 = 2 * EN;                 // number of row-pairs
    int E0  = et * 13;
    int B0  = bt * 16;
    const float* Whh  = d ? Whh_b : Whh_f;
    const float* bvec = d ? bb : bf;
    const float* proj = ws + PROJ_OFF + (size_t)d * VOCAB * 800;
    float* hbuf = ws + HBUF_OFF;
    float* lstm_out = ws + LSTM_OFF;
    int grp = d * 8 + bt;
    unsigned int* flagbase = (unsigned int*)(ws + FLAGS_OFF) + (size_t)grp * 256; // 16 wgs x 16 u32
    unsigned int* myflag = flagbase + (size_t)et * 16;

    __shared__ float hlds[16][208];
    __shared__ float glds[52][17];
    __shared__ int   toklds[2][16];

    int tid = threadIdx.x;
    int rp = tid >> 3, bp = (tid >> 2) & 1, kq = tid & 3;
    bool act = rp < NR2;
    int r0 = 2 * rp, r1 = 2 * rp + 1;
    float bias0 = 0.f, bias1 = 0.f;
    float4 w4[2][13];
#pragma unroll
    for (int i = 0; i < 13; i++) { w4[0][i] = make_float4(0.f,0.f,0.f,0.f); w4[1][i] = make_float4(0.f,0.f,0.f,0.f); }
    if (act) {
        int j0 = (r0 & 3) * HDIM + (E0 + (r0 >> 2));
        int j1 = (r1 & 3) * HDIM + (E0 + (r1 >> 2));
        bias0 = bvec[j0]; bias1 = bvec[j1];
#pragma unroll
        for (int i = 0; i < 13; i++) {
            int k = kq * 52 + 4 * i;
            if (k <= 196) {
                w4[0][i] = *(const float4*)&Whh[(size_t)j0 * HDIM + k];
                w4[1][i] = *(const float4*)&Whh[(size_t)j1 * HDIM + k];
            }
        }
    }
    if (tid < 128) { int b = tid >> 3, c = 200 + (tid & 7); hlds[b][c] = 0.f; }
    if (tid < 16) toklds[0][tid] = sentence[(size_t)(B0 + tid) * TLEN + (d ? (TLEN - 1) : 0)];

    int ub = tid / 13, ue = tid % 13;            // update role: tid<208 => (batch, elem)
    bool uact = (tid < 208) && (ue < EN);
    float creg = 0.f;
    __syncthreads();

#pragma unroll 1
    for (int t = 0; t < TLEN; t++) {
        int t_eff = d ? (TLEN - 1 - t) : t;
        // phase 1: gather x-projections + stage h into LDS (relaxed agent loads)
        float xp0[8], xp1[8];
        if (act && kq == 0) {
#pragma unroll
            for (int bi = 0; bi < 8; bi++) {
                int tk = toklds[t & 1][bp * 8 + bi];
                xp0[bi] = proj[(size_t)tk * 800 + E0 * 4 + r0];
                xp1[bi] = proj[(size_t)tk * 800 + E0 * 4 + r1];
            }
        }
        int pr = t & 1;
        float* hsrc = hbuf + (size_t)(pr * 2 + d) * BATCH * HDIM;
        if (tid < 200) {
            int c4 = tid % 50, brow = tid / 50;
#pragma unroll
            for (int k = 0; k < 4; k++) {
                float* a = hsrc + (size_t)(B0 + brow + 4 * k) * HDIM + 4 * c4;
                float x0 = __hip_atomic_load(a + 0, __ATOMIC_RELAXED, __HIP_MEMORY_SCOPE_AGENT);
                float x1 = __hip_atomic_load(a + 1, __ATOMIC_RELAXED, __HIP_MEMORY_SCOPE_AGENT);
                float x2 = __hip_atomic_load(a + 2, __ATOMIC_RELAXED, __HIP_MEMORY_SCOPE_AGENT);
                float x3 = __hip_atomic_load(a + 3, __ATOMIC_RELAXED, __HIP_MEMORY_SCOPE_AGENT);
                hlds[brow + 4 * k][4 * c4 + 0] = x0;
                hlds[brow + 4 * k][4 * c4 + 1] = x1;
                hlds[brow + 4 * k][4 * c4 + 2] = x2;
                hlds[brow + 4 * k][4 * c4 + 3] = x3;
            }
        }
        __syncthreads();

        // phase 2: h @ Whh^T partial dots (k-quartered), reduce, write gates
        float acc[2][8];
#pragma unroll
        for (int x = 0; x < 2; x++)
#pragma unroll
            for (int bi = 0; bi < 8; bi++) acc[x][bi] = 0.f;
        int kbase = kq * 52;
#pragma unroll
        for (int i = 0; i < 13; i++) {
#pragma unroll
            for (int bi = 0; bi < 8; bi++) {
                float4 hv = *(const float4*)&hlds[bp * 8 + bi][kbase + 4 * i];
                acc[0][bi] += w4[0][i].x * hv.x + w4[0][i].y * hv.y + w4[0][i].z * hv.z + w4[0][i].w * hv.w;
                acc[1][bi] += w4[1][i].x * hv.x + w4[1][i].y * hv.y + w4[1][i].z * hv.z + w4[1][i].w * hv.w;
            }
        }
#pragma unroll
        for (int x = 0; x < 2; x++)
#pragma unroll
            for (int bi = 0; bi < 8; bi++) {
                acc[x][bi] += __shfl_xor(acc[x][bi], 1);
                acc[x][bi] += __shfl_xor(acc[x][bi], 2);
            }
        if (act && kq == 0) {
#pragma unroll
            for (int bi = 0; bi < 8; bi++) {
                glds[r0][bp * 8 + bi] = acc[0][bi] + xp0[bi] + bias0;
                glds[r1][bp * 8 + bi] = acc[1][bi] + xp1[bi] + bias1;
            }
        }
        __syncthreads();

        // phase 3: activations, c/h update, publish h (relaxed agent stores)
        if (uact) {
            float gi = glds[ue * 4 + 0][ub];
            float gf = glds[ue * 4 + 1][ub];
            float gg = glds[ue * 4 + 2][ub];
            float go = glds[ue * 4 + 3][ub];
            float si = 1.f / (1.f + expf(-gi));
            float sf = 1.f / (1.f + expf(-gf));
            float so = 1.f / (1.f + expf(-go));
            creg = sf * creg + si * tanhf(gg);
            float hval = so * tanhf(creg);
            int pw = 1 - pr;
            __hip_atomic_store(&hbuf[((size_t)(pw * 2 + d) * BATCH + B0 + ub) * HDIM + E0 + ue],
                               hval, __ATOMIC_RELAXED, __HIP_MEMORY_SCOPE_AGENT);
            lstm_out[((size_t)t_eff * BATCH + B0 + ub) * 400 + d * HDIM + E0 + ue] = hval;
        }
        if (tid < 16 && t + 1 < TLEN)
            toklds[(t + 1) & 1][tid] = sentence[(size_t)(B0 + tid) * TLEN + (d ? (TLEN - 2 - t) : (t + 1))];
        __syncthreads();   // vmcnt drain: relaxed h-stores acked at coherence point

        // phase 4: distributed flag barrier — all relaxed, no fences
        if (tid == 0)
            __hip_atomic_store(myflag, (unsigned)(t + 1), __ATOMIC_RELAXED, __HIP_MEMORY_SCOPE_AGENT);
        if (tid < 16) {
            unsigned int* f = flagbase + (size_t)tid * 16;
            while (__hip_atomic_load(f, __ATOMIC_RELAXED, __HIP_MEMORY_SCOPE_AGENT) < (unsigned)(t + 1))
                __builtin_amdgcn_s_sleep(2);
        }
        __syncthreads();
    }
}

// ---------------- K3: emissions em = lstm_out @ W_fc^T + b_fc ----------------
__global__ __launch_bounds__(256) void k3_em(const float* __restrict__ Wfc,
                                             const float* __restrict__ bfc,
                                             float* __restrict__ ws)
{
    __shared__ float llds[15][404];
    __shared__ float wlds[17][404];
    const float* lstm = ws + LSTM_OFF;
    float* em = ws + EM_OFF;
    int n0 = blockIdx.x * 15;
    int tid = threadIdx.x;
    for (int idx = tid; idx < 15 * 400; idx += 256) {
        int r = idx / 400, c = idx % 400;
        int n = n0 + r;
        llds[r][c] = (n < BATCH * TLEN) ? lstm[(size_t)n * 400 + c] : 0.f;
    }
    for (int idx = tid; idx < 17 * 400; idx += 256) {
        int r = idx / 400, c = idx % 400;
        wlds[r][c] = Wfc[r * 400 + c];
    }
    __syncthreads();
    if (tid < 255) {
        int tk = tid / 17, k = tid % 17;
        int n = n0 + tk;
        if (n < BATCH * TLEN) {
            float acc = 0.f;
#pragma unroll
            for (int i = 0; i < 100; i++) {
                float4 a  = *(const float4*)&llds[tk][4 * i];
                float4 wv = *(const float4*)&wlds[k][4 * i];
                acc += a.x * wv.x + a.y * wv.y + a.z * wv.z + a.w * wv.w;
            }
            em[(size_t)n * KTAG + k] = acc + bfc[k];
        }
    }
}

// ---------------- K4: bin_scores = mean_t(lstm_out) @ W_bin^T + b_bin ----------------
__global__ __launch_bounds__(256) void k4_bin(const float* __restrict__ Wbin,
                                              const float* __restrict__ bbin,
                                              float* __restrict__ ws,
                                              float* __restrict__ out)
{
    int b = blockIdx.x, tid = threadIdx.x;
    const float* lstm = ws + LSTM_OFF;
    __shared__ float m_lds[400];
    float a0 = 0.f, a1 = 0.f;
#pragma unroll 4
    for (int t = 0; t < TLEN; t++) {
        const float* rowp = lstm + ((size_t)t * BATCH + b) * 400;
        a0 += rowp[tid];
        if (tid < 144) a1 += rowp[256 + tid];
    }
    m_lds[tid] = a0 * (1.f / 512.f);
    if (tid < 144) m_lds[256 + tid] = a1 * (1.f / 512.f);
    __syncthreads();
    int wv = tid >> 6, lane = tid & 63;
    if (wv < 2) {
        float p = 0.f;
        for (int j = lane; j < 400; j += 64) p += m_lds[j] * Wbin[wv * 400 + j];
#pragma unroll
        for (int off = 32; off > 0; off >>= 1) p += __shfl_down(p, off);
        if (lane == 0) out[(size_t)BATCH * TLEN + b * 2 + wv] = p + bbin[wv];
    }
}

// ---------------- K5: masked Viterbi decode + traceback ----------------
__global__ __launch_bounds__(64) void k5_vit(const int* __restrict__ masks,
                                             const float* __restrict__ trans,
                                             const float* __restrict__ startv,
                                             const float* __restrict__ endv,
                                             const float* __restrict__ ws,
                                             float* __restrict__ out)
{
    int b = blockIdx.x, lane = threadIdx.x;
    const float* em = ws + EM_OFF;
    __shared__ float emlds[TLEN * KTAG];
    __shared__ unsigned char bpl[TLEN * KTAG];
    __shared__ int mlds[TLEN];
    __shared__ unsigned char tagl[TLEN];
    __shared__ float slds[KTAG];
    __shared__ float fin[KTAG];

    for (int idx = lane; idx < TLEN * KTAG; idx += 64) {
        int tt = idx / KTAG, j = idx - tt * KTAG;
        emlds[idx] = em[((size_t)tt * BATCH + b) * KTAG + j];
    }
    for (int idx = lane; idx < TLEN; idx += 64) mlds[idx] = masks[(size_t)b * TLEN + idx];
    bool on = lane < KTAG;
    float tr[KTAG];
    if (on) {
#pragma unroll
        for (int i = 0; i < KTAG; i++) tr[i] = trans[i * KTAG + lane];
    }
    __syncthreads();
    float sown = 0.f;
    if (on) { sown = startv[lane] + emlds[lane]; slds[lane] = sown; }
    __syncthreads();
#pragma unroll 1
    for (int t = 1; t < TLEN; t++) {
        int m = mlds[t];
        float ns = sown; int idx = lane;
        if (on) {
            float best = -3.4e38f; int bi = 0;
#pragma unroll
            for (int i = 0; i < KTAG; i++) {
                float vv = slds[i] + tr[i];
                if (vv > best) { best = vv; bi = i; }   // strict > => first max (matches jnp.argmax)
            }
            if (m != 0) { ns = best + emlds[t * KTAG + lane]; idx = bi; }
        }
        __syncthreads();
        if (on) { sown = ns; slds[lane] = ns; bpl[t * KTAG + lane] = (unsigned char)idx; }
        __syncthreads();
    }
    if (on) fin[lane] = sown + endv[lane];
    __syncthreads();
    if (lane == 0) {
        float bb = -3.4e38f; int bi = 0;
#pragma unroll
        for (int i = 0; i < KTAG; i++) if (fin[i] > bb) { bb = fin[i]; bi = i; }
        int cur = bi;
        tagl[TLEN - 1] = (unsigned char)cur;
        for (int t = TLEN - 1; t >= 1; t--) {
            cur = bpl[t * KTAG + cur];
            tagl[t - 1] = (unsigned char)cur;
        }
    }
    __syncthreads();
    for (int s = lane; s < TLEN; s += 64) out[(size_t)b * TLEN + s] = (float)tagl[s];
}

extern "C" void kernel_launch(void* const* d_in, const int* in_sizes, int n_in,
                              void* d_out, int out_size, void* d_ws, size_t ws_size,
                              hipStream_t stream)
{
    (void)in_sizes; (void)n_in; (void)out_size; (void)ws_size;
    const int*   sentence = (const int*)d_in[0];
    const int*   masks    = (const int*)d_in[1];
    const float* emb      = (const float*)d_in[2];
    const float* Wih_f    = (const float*)d_in[3];
    const float* Whh_f    = (const float*)d_in[4];
    const float* b_f      = (const float*)d_in[5];
    const float* Wih_b    = (const float*)d_in[6];
    const float* Whh_b    = (const float*)d_in[7];
    const float* b_b      = (const float*)d_in[8];
    const float* W_fc     = (const float*)d_in[9];
    const float* b_fc     = (const float*)d_in[10];
    const float* W_bin    = (const float*)d_in[11];
    const float* b_bin    = (const float*)d_in[12];
    const float* trans    = (const float*)d_in[13];
    const float* startv   = (const float*)d_in[14];
    const float* endv     = (const float*)d_in[15];
    float* ws  = (float*)d_ws;
    float* out = (float*)d_out;

    // zero h-state (parity 0 read at t=0) and sync flags, every launch (deterministic)
    hipMemsetAsync(ws + HBUF_OFF, 0, 102400 * sizeof(float), stream);
    hipMemsetAsync(ws + FLAGS_OFF, 0, 4096 * sizeof(float), stream);

    k1_proj<<<626, 256, 0, stream>>>(emb, Wih_f, Wih_b, ws);

    {
        const int* s_ = sentence; const float* wf_ = Whh_f; const float* bf_ = b_f;
        const float* wb_ = Whh_b; const float* bb_ = b_b; float* ws_ = ws;
        void* args[] = { (void*)&s_, (void*)&wf_, (void*)&bf_, (void*)&wb_, (void*)&bb_, (void*)&ws_ };
        hipLaunchCooperativeKernel((void*)k2_lstm, dim3(256), dim3(256), args, 0, stream);
    }

    k3_em<<<4370, 256, 0, stream>>>(W_fc, b_fc, ws);
    k4_bin<<<128, 256, 0, stream>>>(W_bin, b_bin, ws, out);
    k5_vit<<<128, 64, 0, stream>>>(masks, trans, startv, endv, ws, out);
}

// Round 6
// 6721.490 us; speedup vs baseline: 5.2311x; 1.9361x over previous
//
#include <hip/hip_runtime.h>
#include <math.h>

#define VOCAB 20000
#define EDIM  100
#define HDIM  200
#define KTAG  17
#define BATCH 128
#define TLEN  512

// ws layout (float offsets)
static const size_t PROJ_OFF = 0;              // 2 * 20000 * 800 = 32,000,000 floats
static const size_t LSTM_OFF = 32102464;       // 512*128*400 = 26,214,400
static const size_t EM_OFF   = 58316864;       // 512*128*17 = 1,114,112
// W2 (packed Whh, 2*50*200*4 float4 = 320,000 floats) overlaps the EM region:
// written by k0, read by k2, dead once k3 overwrites em. No flags, no hbuf.
// total = 59,430,976 floats = 237,723,904 bytes (unchanged)

// ---------------- K0: pack Whh into stream-friendly layout ----------------
// W2f4[d][k4][e][g] = Whh_d[row = g*200+e][k = 4*k4 .. 4*k4+3]
// k2's thread (kh,e) then reads 4 contiguous float4 (g=0..3) per k4; lanes
// (consecutive e) are 64B apart -> coalesced streaming, L2-resident (1.28 MB).
__global__ __launch_bounds__(256) void k0_pack(const float* __restrict__ Whh_f,
                                               const float* __restrict__ Whh_b,
                                               float* __restrict__ ws)
{
    int i = blockIdx.x * 256 + threadIdx.x;
    if (i >= 80000) return;
    int d = i / 40000, r = i % 40000;
    int k4 = r / 800, r2 = r % 800;
    int e = r2 >> 2, g = r2 & 3;
    const float* W = d ? Whh_b : Whh_f;
    float4 v = *(const float4*)(W + (size_t)(g * 200 + e) * 200 + 4 * k4);
    ((float4*)(ws + EM_OFF))[i] = v;
}

// ---------------- K1: per-vocab input projections ----------------
__global__ __launch_bounds__(256) void k1_proj(const float* __restrict__ emb,
                                               const float* __restrict__ Wf,
                                               const float* __restrict__ Wb,
                                               float* __restrict__ ws)
{
    int blk = blockIdx.x;
    int d = blk / 313, vt = blk % 313;
    const float* Wih = d ? Wb : Wf;
    float* proj = ws + PROJ_OFF + (size_t)d * VOCAB * 800;
    __shared__ float elds[64][104];
    __shared__ float olds[64][4][26];
    int tid = threadIdx.x;
    for (int idx = tid; idx < 64 * EDIM; idx += 256) {
        int r = idx / EDIM, c = idx % EDIM;
        int v = vt * 64 + r;
        elds[r][c] = (v < VOCAB) ? emb[(size_t)v * EDIM + c] : 0.f;
    }
    __syncthreads();
    int lane = tid & 63, wq = tid >> 6;
    float4 er[25];
#pragma unroll
    for (int i = 0; i < 25; i++) er[i] = *(const float4*)&elds[lane][4 * i];
#pragma unroll 1
    for (int round = 0; round < 8; round++) {
#pragma unroll 1
        for (int m = 0; m < 25; m++) {
            int oj = wq * 200 + round * 25 + m;      // wave-uniform
            int e = oj >> 2, g = oj & 3;
            int row = __builtin_amdgcn_readfirstlane(g * HDIM + e);
            const float* wrow = Wih + (size_t)row * EDIM;
            float acc = 0.f;
#pragma unroll
            for (int i = 0; i < 25; i++) {
                float4 w4 = *(const float4*)&wrow[4 * i];
                acc += w4.x * er[i].x + w4.y * er[i].y + w4.z * er[i].z + w4.w * er[i].w;
            }
            olds[lane][wq][m] = acc;
        }
        __syncthreads();
        for (int idx = tid; idx < 6400; idx += 256) {
            int vloc = idx / 100, rem = idx % 100;
            int q = rem / 25, c = rem % 25;
            int vv = vt * 64 + vloc;
            if (vv < VOCAB) proj[(size_t)vv * 800 + q * 200 + round * 25 + c] = olds[vloc][q][c];
        }
        __syncthreads();
    }
}

// ---------------- K2: bidirectional LSTM, ZERO cross-wg communication ----------------
// R5 redesign: batch elements are independent -> each wg owns (dir, 4 batches)
// completely. h/c state is wg-local (LDS double buffer + regs); Whh is streamed
// from L2 per step (packed by k0, stays L2-resident). The only per-step sync is
// __syncthreads. Regular launch, 64 wgs x 512 threads.
// Thread map: kh = tid>>8 (k-half), te = tid&255 (h-elem, active te<200).
// Thread (kh,te) owns gate rows {g*200+te} over k in [kh*100, kh*100+100).
__device__ __forceinline__ void fma4x4(const float4& W0, const float4& W1,
                                       const float4& W2c, const float4& W3,
                                       const float4& H,
                                       float& aI, float& aF, float& aG, float& aO)
{
    aI += W0.x * H.x + W0.y * H.y + W0.z * H.z + W0.w * H.w;
    aF += W1.x * H.x + W1.y * H.y + W1.z * H.z + W1.w * H.w;
    aG += W2c.x * H.x + W2c.y * H.y + W2c.z * H.z + W2c.w * H.w;
    aO += W3.x * H.x + W3.y * H.y + W3.z * H.z + W3.w * H.w;
}

__global__ __launch_bounds__(512, 2) void k2_lstm(const int* __restrict__ sentence,
                                                  const float* __restrict__ bf,
                                                  const float* __restrict__ bb,
                                                  float* __restrict__ ws)
{
    int w = blockIdx.x;               // 64 = 2 dirs x 32 batch-tiles
    int d = w >> 5, bt = w & 31;
    int B0 = bt * 4;
    const float* bvec = d ? bb : bf;
    const float* proj = ws + PROJ_OFF + (size_t)d * VOCAB * 800;
    const float4* W2 = (const float4*)(ws + EM_OFF) + (size_t)d * 40000;
    float* lstm_out = ws + LSTM_OFF;

    __shared__ float h_lds[2][4][208];
    __shared__ float red[200][17];
    __shared__ int   tok[4][TLEN];

    int tid = threadIdx.x;
    int kh = tid >> 8, te = tid & 255;
    bool active = te < 200;

    // preload all tokens for this wg's 4 batches (coalesced, once)
#pragma unroll
    for (int b = 0; b < 4; b++)
        tok[b][tid] = sentence[(size_t)(B0 + b) * TLEN + tid];
    // zero h parity 0
    for (int i = tid; i < 4 * 208; i += 512) ((float*)h_lds[0])[i] = 0.f;

    float bias_i = 0.f, bias_f = 0.f, bias_g = 0.f, bias_o = 0.f;
    if (kh == 0 && active) {
        bias_i = bvec[te];
        bias_f = bvec[200 + te];
        bias_g = bvec[400 + te];
        bias_o = bvec[600 + te];
    }
    const float4* wbase = W2 + ((size_t)(kh * 25) * 200 + (active ? te : 0)) * 4;
    float c0 = 0.f, c1 = 0.f, c2 = 0.f, c3 = 0.f;
    __syncthreads();

#pragma unroll 1
    for (int t = 0; t < TLEN; t++) {
        int t_eff = d ? (TLEN - 1 - t) : t;
        int p = t & 1;

        // xp gathers: issued at step top, consumed in the epilogue (~2.5us later)
        float4 xp0, xp1, xp2, xp3;
        if (kh == 0 && active) {
            xp0 = *(const float4*)(proj + (size_t)tok[0][t_eff] * 800 + 4 * te);
            xp1 = *(const float4*)(proj + (size_t)tok[1][t_eff] * 800 + 4 * te);
            xp2 = *(const float4*)(proj + (size_t)tok[2][t_eff] * 800 + 4 * te);
            xp3 = *(const float4*)(proj + (size_t)tok[3][t_eff] * 800 + 4 * te);
        }

        float aI0 = 0.f, aF0 = 0.f, aG0 = 0.f, aO0 = 0.f;
        float aI1 = 0.f, aF1 = 0.f, aG1 = 0.f, aO1 = 0.f;
        float aI2 = 0.f, aF2 = 0.f, aG2 = 0.f, aO2 = 0.f;
        float aI3 = 0.f, aF3 = 0.f, aG3 = 0.f, aO3 = 0.f;

        if (active) {
            const float* hp0 = &h_lds[p][0][kh * 100];
            const float* hp1 = &h_lds[p][1][kh * 100];
            const float* hp2 = &h_lds[p][2][kh * 100];
            const float* hp3 = &h_lds[p][3][kh * 100];
            const float4* wp = wbase;
            // 2-deep double-buffered pipeline over 25 k4-groups
            float4 wA0, wA1, wA2, wA3, wB0, wB1, wB2, wB3;
            float4 hA0, hA1, hA2, hA3, hB0, hB1, hB2, hB3;
#define LOAD_A(off) \
            wA0 = wp[0]; wA1 = wp[1]; wA2 = wp[2]; wA3 = wp[3]; wp += 800; \
            hA0 = *(const float4*)(hp0 + (off)); hA1 = *(const float4*)(hp1 + (off)); \
            hA2 = *(const float4*)(hp2 + (off)); hA3 = *(const float4*)(hp3 + (off));
#define LOAD_B(off) \
            wB0 = wp[0]; wB1 = wp[1]; wB2 = wp[2]; wB3 = wp[3]; wp += 800; \
            hB0 = *(const float4*)(hp0 + (off)); hB1 = *(const float4*)(hp1 + (off)); \
            hB2 = *(const float4*)(hp2 + (off)); hB3 = *(const float4*)(hp3 + (off));
#define STEP_A \
            fma4x4(wA0, wA1, wA2, wA3, hA0, aI0, aF0, aG0, aO0); \
            fma4x4(wA0, wA1, wA2, wA3, hA1, aI1, aF1, aG1, aO1); \
            fma4x4(wA0, wA1, wA2, wA3, hA2, aI2, aF2, aG2, aO2); \
            fma4x4(wA0, wA1, wA2, wA3, hA3, aI3, aF3, aG3, aO3);
#define STEP_B \
            fma4x4(wB0, wB1, wB2, wB3, hB0, aI0, aF0, aG0, aO0); \
            fma4x4(wB0, wB1, wB2, wB3, hB1, aI1, aF1, aG1, aO1); \
            fma4x4(wB0, wB1, wB2, wB3, hB2, aI2, aF2, aG2, aO2); \
            fma4x4(wB0, wB1, wB2, wB3, hB3, aI3, aF3, aG3, aO3);
            LOAD_A(0)
            LOAD_B(4)
            int off = 8;
#pragma unroll 1
            for (int jp = 0; jp < 11; jp++) {
                STEP_A
                LOAD_A(off)
                off += 4;
                STEP_B
                LOAD_B(off)
                off += 4;
            }
            STEP_A
            LOAD_A(96)
            STEP_B
            STEP_A
#undef LOAD_A
#undef LOAD_B
#undef STEP_A
#undef STEP_B
        }

        // kh=1 contributes its k-half via LDS
        if (kh == 1 && active) {
            red[te][0]  = aI0; red[te][1]  = aF0; red[te][2]  = aG0; red[te][3]  = aO0;
            red[te][4]  = aI1; red[te][5]  = aF1; red[te][6]  = aG1; red[te][7]  = aO1;
            red[te][8]  = aI2; red[te][9]  = aF2; red[te][10] = aG2; red[te][11] = aO2;
            red[te][12] = aI3; red[te][13] = aF3; red[te][14] = aG3; red[te][15] = aO3;
        }
        __syncthreads();

        if (kh == 0 && active) {
            int pn = p ^ 1;
            float gi, gf, gg, go, sI, sF, sO, hv;
            // batch 0
            gi = aI0 + red[te][0] + xp0.x + bias_i;
            gf = aF0 + red[te][1] + xp0.y + bias_f;
            gg = aG0 + red[te][2] + xp0.z + bias_g;
            go = aO0 + red[te][3] + xp0.w + bias_o;
            sI = 1.f / (1.f + expf(-gi)); sF = 1.f / (1.f + expf(-gf)); sO = 1.f / (1.f + expf(-go));
            c0 = sF * c0 + sI * tanhf(gg);
            hv = sO * tanhf(c0);
            h_lds[pn][0][te] = hv;
            lstm_out[((size_t)t_eff * BATCH + B0 + 0) * 400 + d * 200 + te] = hv;
            // batch 1
            gi = aI1 + red[te][4] + xp1.x + bias_i;
            gf = aF1 + red[te][5] + xp1.y + bias_f;
            gg = aG1 + red[te][6] + xp1.z + bias_g;
            go = aO1 + red[te][7] + xp1.w + bias_o;
            sI = 1.f / (1.f + expf(-gi)); sF = 1.f / (1.f + expf(-gf)); sO = 1.f / (1.f + expf(-go));
            c1 = sF * c1 + sI * tanhf(gg);
            hv = sO * tanhf(c1);
            h_lds[pn][1][te] = hv;
            lstm_out[((size_t)t_eff * BATCH + B0 + 1) * 400 + d * 200 + te] = hv;
            // batch 2
            gi = aI2 + red[te][8]  + xp2.x + bias_i;
            gf = aF2 + red[te][9]  + xp2.y + bias_f;
            gg = aG2 + red[te][10] + xp2.z + bias_g;
            go = aO2 + red[te][11] + xp2.w + bias_o;
            sI = 1.f / (1.f + expf(-gi)); sF = 1.f / (1.f + expf(-gf)); sO = 1.f / (1.f + expf(-go));
            c2 = sF * c2 + sI * tanhf(gg);
            hv = sO * tanhf(c2);
            h_lds[pn][2][te] = hv;
            lstm_out[((size_t)t_eff * BATCH + B0 + 2) * 400 + d * 200 + te] = hv;
            // batch 3
            gi = aI3 + red[te][12] + xp3.x + bias_i;
            gf = aF3 + red[te][13] + xp3.y + bias_f;
            gg = aG3 + red[te][14] + xp3.z + bias_g;
            go = aO3 + red[te][15] + xp3.w + bias_o;
            sI = 1.f / (1.f + expf(-gi)); sF = 1.f / (1.f + expf(-gf)); sO = 1.f / (1.f + expf(-go));
            c3 = sF * c3 + sI * tanhf(gg);
            hv = sO * tanhf(c3);
            h_lds[pn][3][te] = hv;
            lstm_out[((size_t)t_eff * BATCH + B0 + 3) * 400 + d * 200 + te] = hv;
        }
        __syncthreads();
    }
}

// ---------------- K3: emissions em = lstm_out @ W_fc^T + b_fc ----------------
__global__ __launch_bounds__(256) void k3_em(const float* __restrict__ Wfc,
                                             const float* __restrict__ bfc,
                                             float* __restrict__ ws)
{
    __shared__ float llds[15][404];
    __shared__ float wlds[17][404];
    const float* lstm = ws + LSTM_OFF;
    float* em = ws + EM_OFF;
    int n0 = blockIdx.x * 15;
    int tid = threadIdx.x;
    for (int idx = tid; idx < 15 * 400; idx += 256) {
        int r = idx / 400, c = idx % 400;
        int n = n0 + r;
        llds[r][c] = (n < BATCH * TLEN) ? lstm[(size_t)n * 400 + c] : 0.f;
    }
    for (int idx = tid; idx < 17 * 400; idx += 256) {
        int r = idx / 400, c = idx % 400;
        wlds[r][c] = Wfc[r * 400 + c];
    }
    __syncthreads();
    if (tid < 255) {
        int tk = tid / 17, k = tid % 17;
        int n = n0 + tk;
        if (n < BATCH * TLEN) {
            float acc = 0.f;
#pragma unroll
            for (int i = 0; i < 100; i++) {
                float4 a  = *(const float4*)&llds[tk][4 * i];
                float4 wv = *(const float4*)&wlds[k][4 * i];
                acc += a.x * wv.x + a.y * wv.y + a.z * wv.z + a.w * wv.w;
            }
            em[(size_t)n * KTAG + k] = acc + bfc[k];
        }
    }
}

// ---------------- K4: bin_scores = mean_t(lstm_out) @ W_bin^T + b_bin ----------------
__global__ __launch_bounds__(256) void k4_bin(const float* __restrict__ Wbin,
                                              const float* __restrict__ bbin,
                                              float* __restrict__ ws,
                                              float* __restrict__ out)
{
    int b = blockIdx.x, tid = threadIdx.x;
    const float* lstm = ws + LSTM_OFF;
    __shared__ float m_lds[400];
    float a0 = 0.f, a1 = 0.f;
#pragma unroll 4
    for (int t = 0; t < TLEN; t++) {
        const float* rowp = lstm + ((size_t)t * BATCH + b) * 400;
        a0 += rowp[tid];
        if (tid < 144) a1 += rowp[256 + tid];
    }
    m_lds[tid] = a0 * (1.f / 512.f);
    if (tid < 144) m_lds[256 + tid] = a1 * (1.f / 512.f);
    __syncthreads();
    int wv = tid >> 6, lane = tid & 63;
    if (wv < 2) {
        float p = 0.f;
        for (int j = lane; j < 400; j += 64) p += m_lds[j] * Wbin[wv * 400 + j];
#pragma unroll
        for (int off = 32; off > 0; off >>= 1) p += __shfl_down(p, off);
        if (lane == 0) out[(size_t)BATCH * TLEN + b * 2 + wv] = p + bbin[wv];
    }
}

// ---------------- K5: masked Viterbi decode + traceback ----------------
__global__ __launch_bounds__(64) void k5_vit(const int* __restrict__ masks,
                                             const float* __restrict__ trans,
                                             const float* __restrict__ startv,
                                             const float* __restrict__ endv,
                                             const float* __restrict__ ws,
                                             float* __restrict__ out)
{
    int b = blockIdx.x, lane = threadIdx.x;
    const float* em = ws + EM_OFF;
    __shared__ float emlds[TLEN * KTAG];
    __shared__ unsigned char bpl[TLEN * KTAG];
    __shared__ int mlds[TLEN];
    __shared__ unsigned char tagl[TLEN];
    __shared__ float slds[KTAG];
    __shared__ float fin[KTAG];

    for (int idx = lane; idx < TLEN * KTAG; idx += 64) {
        int tt = idx / KTAG, j = idx - tt * KTAG;
        emlds[idx] = em[((size_t)tt * BATCH + b) * KTAG + j];
    }
    for (int idx = lane; idx < TLEN; idx += 64) mlds[idx] = masks[(size_t)b * TLEN + idx];
    bool on = lane < KTAG;
    float tr[KTAG];
    if (on) {
#pragma unroll
        for (int i = 0; i < KTAG; i++) tr[i] = trans[i * KTAG + lane];
    }
    __syncthreads();
    float sown = 0.f;
    if (on) { sown = startv[lane] + emlds[lane]; slds[lane] = sown; }
    __syncthreads();
#pragma unroll 1
    for (int t = 1; t < TLEN; t++) {
        int m = mlds[t];
        float ns = sown; int idx = lane;
        if (on) {
            float best = -3.4e38f; int bi = 0;
#pragma unroll
            for (int i = 0; i < KTAG; i++) {
                float vv = slds[i] + tr[i];
                if (vv > best) { best = vv; bi = i; }   // strict > => first max (matches jnp.argmax)
            }
            if (m != 0) { ns = best + emlds[t * KTAG + lane]; idx = bi; }
        }
        __syncthreads();
        if (on) { sown = ns; slds[lane] = ns; bpl[t * KTAG + lane] = (unsigned char)idx; }
        __syncthreads();
    }
    if (on) fin[lane] = sown + endv[lane];
    __syncthreads();
    if (lane == 0) {
        float bb = -3.4e38f; int bi = 0;
#pragma unroll
        for (int i = 0; i < KTAG; i++) if (fin[i] > bb) { bb = fin[i]; bi = i; }
        int cur = bi;
        tagl[TLEN - 1] = (unsigned char)cur;
        for (int t = TLEN - 1; t >= 1; t--) {
            cur = bpl[t * KTAG + cur];
            tagl[t - 1] = (unsigned char)cur;
        }
    }
    __syncthreads();
    for (int s = lane; s < TLEN; s += 64) out[(size_t)b * TLEN + s] = (float)tagl[s];
}

extern "C" void kernel_launch(void* const* d_in, const int* in_sizes, int n_in,
                              void* d_out, int out_size, void* d_ws, size_t ws_size,
                              hipStream_t stream)
{
    (void)in_sizes; (void)n_in; (void)out_size; (void)ws_size;
    const int*   sentence = (const int*)d_in[0];
    const int*   masks    = (const int*)d_in[1];
    const float* emb      = (const float*)d_in[2];
    const float* Wih_f    = (const float*)d_in[3];
    const float* Whh_f    = (const float*)d_in[4];
    const float* b_f      = (const float*)d_in[5];
    const float* Wih_b    = (const float*)d_in[6];
    const float* Whh_b    = (const float*)d_in[7];
    const float* b_b      = (const float*)d_in[8];
    const float* W_fc     = (const float*)d_in[9];
    const float* b_fc     = (const float*)d_in[10];
    const float* W_bin    = (const float*)d_in[11];
    const float* b_bin    = (const float*)d_in[12];
    const float* trans    = (const float*)d_in[13];
    const float* startv   = (const float*)d_in[14];
    const float* endv     = (const float*)d_in[15];
    float* ws  = (float*)d_ws;
    float* out = (float*)d_out;

    k0_pack<<<313, 256, 0, stream>>>(Whh_f, Whh_b, ws);
    k1_proj<<<626, 256, 0, stream>>>(emb, Wih_f, Wih_b, ws);
    k2_lstm<<<64, 512, 0, stream>>>(sentence, b_f, b_b, ws);
    k3_em<<<4370, 256, 0, stream>>>(W_fc, b_fc, ws);
    k4_bin<<<128, 256, 0, stream>>>(W_bin, b_bin, ws, out);
    k5_vit<<<128, 64, 0, stream>>>(masks, trans, startv, endv, ws, out);
}